// Round 8
// baseline (190.547 us; speedup 1.0000x reference)
//
#include <hip/hip_runtime.h>
#include <math.h>

// Problem constants
#define BB 4
#define SS 4096
#define DD 64
#define HH 16
#define PI_C 3.1415f

// ---------------------------------------------------------------------------
// ws layout (bytes):
//   0        : wT    bf16 wq|wk|wv|wd x 65536 shorts   524,288
//   524288   : kvb   bf16 [64bh][z*64+x]               524,288
//   1048576  : kvsb  bf16                              524,288
//   1572864  : ksums fp32 [64bh][128]                   32,768
//   1605632  : pkv   fp32 [8][64bh][z*64+x]          8,388,608
//   9994240  : pkvs  fp32                            8,388,608
//   18382848 : pks   fp32 [8][64bh][128]               262,144
//   total ~18.6 MB
// ---------------------------------------------------------------------------

typedef __attribute__((ext_vector_type(8))) short short8;   // bf16 MFMA operand
typedef __attribute__((ext_vector_type(4))) float f32x4;    // MFMA C/D frag

#define MFMA(a, b, c) __builtin_amdgcn_mfma_f32_16x16x32_bf16(a, b, c, 0, 0, 0)

__device__ __forceinline__ short f2bf(float f) {
    union { float f; unsigned u; } v; v.f = f;
    unsigned r = v.u + 0x7FFFu + ((v.u >> 16) & 1u);   // RNE
    return (short)(r >> 16);
}
__device__ __forceinline__ float bf2f(short s) {
    union { unsigned u; float f; } v;
    v.u = ((unsigned)(unsigned short)s) << 16;
    return v.f;
}
__device__ __forceinline__ short8 cvt8(float4 a, float4 b) {
    short8 r;
    r[0] = f2bf(a.x); r[1] = f2bf(a.y); r[2] = f2bf(a.z); r[3] = f2bf(a.w);
    r[4] = f2bf(b.x); r[5] = f2bf(b.y); r[6] = f2bf(b.z); r[7] = f2bf(b.w);
    return r;
}
__device__ __forceinline__ float elu1(float x) { return x > 0.f ? x + 1.f : __expf(x); }
__device__ __forceinline__ void st4(short* p, short a, short b, short c, short d) {
    union { uint2 u; short s[4]; } x;
    x.s[0] = a; x.s[1] = b; x.s[2] = c; x.s[3] = d;
    *reinterpret_cast<uint2*>(p) = x.u;
}

// ---------------------------------------------------------------------------
// Transpose + bf16-convert weights into per-head [out_col][in_dim] layout.
__global__ __launch_bounds__(256) void k_prep(
    const float* __restrict__ wq, const float* __restrict__ wk,
    const float* __restrict__ wv, const float* __restrict__ wd,
    short* __restrict__ dst)
{
    const int h = blockIdx.x, y = blockIdx.y, t = threadIdx.x;
    const float* src = (y == 0) ? wq : (y == 1) ? wk : (y == 2) ? wv : wd;
    const int rs = (y < 3) ? 1024 : 64;
    const size_t srcbase = (y < 3) ? (size_t)(h * 64) : (size_t)(h * 4096);
    short* dm = dst + (size_t)y * 65536 + (size_t)h * 4096;
#pragma unroll
    for (int j = 0; j < 4; ++j) {
        int idx = j * 1024 + t * 4;
        int r = idx >> 6, c = idx & 63;
        float4 v = *reinterpret_cast<const float4*>(src + (size_t)r * rs + srcbase + c);
        dm[(c + 0) * 64 + r] = f2bf(v.x);
        dm[(c + 1) * 64 + r] = f2bf(v.y);
        dm[(c + 2) * 64 + r] = f2bf(v.z);
        dm[(c + 3) * 64 + r] = f2bf(v.w);
    }
}

// ---------------------------------------------------------------------------
// Phase 1 v2: double-buffered projected tiles, ONE barrier per 64-s iter.
// Iter it: project tile it+1 into buf p^1 (from regs prefetched 2 iters ago)
// while kv/kvs GEMM consumes buf p; global K/V prefetched 3 ahead.
__global__ __launch_bounds__(256, 2) void k_phase1(
    const float* __restrict__ key, const float* __restrict__ value,
    const float* __restrict__ wk_b, const float* __restrict__ wv_b,
    const short* __restrict__ wkTb, const short* __restrict__ wvTb,
    float* __restrict__ pkv, float* __restrict__ pkvs,
    float* __restrict__ pks)
{
    const int chunk = blockIdx.x, h = blockIdx.y, b = blockIdx.z;
    const int t = threadIdx.x, w = t >> 6, l = t & 63;
    const int lane15 = l & 15, q8 = (l >> 4) * 8, q4 = (l >> 4) * 4;

    __shared__ short kT[2][64 * 72], vT[2][64 * 72], vsT[2][64 * 72];
    __shared__ short swk[64 * 72], swv[64 * 72];
    __shared__ float ssin[512];
    __shared__ float sbk[64], sbv[64];
    __shared__ float sred[512];

    // ---- stage weights (LDS, once) + ssin + biases ----
    {
        const short8* gk = reinterpret_cast<const short8*>(wkTb + (size_t)h * 4096);
        const short8* gv = reinterpret_cast<const short8*>(wvTb + (size_t)h * 4096);
#pragma unroll
        for (int cc = 0; cc < 2; ++cc) {
            const int idx = t * 2 + cc;
            const int row = idx >> 3, c8 = (idx & 7) * 8;
            *reinterpret_cast<short8*>(&swk[row * 72 + c8]) = gk[idx];
            *reinterpret_cast<short8*>(&swv[row * 72 + c8]) = gv[idx];
        }
    }
    ssin[t]       = __sinf(PI_C * (float)(chunk * 512 + t)       * (1.f / 4096.f));
    ssin[t + 256] = __sinf(PI_C * (float)(chunk * 512 + t + 256) * (1.f / 4096.f));
    if (t < 64) sbk[t] = wk_b[h * 64 + t];
    else if (t < 128) sbv[t - 64] = wv_b[h * 64 + (t - 64)];

    float4 gA[8], gB[8];
    auto loadg = [&](float4* g, int it) {
        const size_t gaddr = ((size_t)b * SS + chunk * 512 + it * 64 + w * 16 + lane15) * 64 + q8;
        g[0] = *reinterpret_cast<const float4*>(key + gaddr);
        g[1] = *reinterpret_cast<const float4*>(key + gaddr + 4);
        g[2] = *reinterpret_cast<const float4*>(key + gaddr + 32);
        g[3] = *reinterpret_cast<const float4*>(key + gaddr + 36);
        g[4] = *reinterpret_cast<const float4*>(value + gaddr);
        g[5] = *reinterpret_cast<const float4*>(value + gaddr + 4);
        g[6] = *reinterpret_cast<const float4*>(value + gaddr + 32);
        g[7] = *reinterpret_cast<const float4*>(value + gaddr + 36);
    };
    auto projstore = [&](const float4* g, int it, int pb) {
        short8 ak0 = cvt8(g[0], g[1]), ak1 = cvt8(g[2], g[3]);
        short8 av0 = cvt8(g[4], g[5]), av1 = cvt8(g[6], g[7]);
        f32x4 ckp[4], cvp[4];
#pragma unroll
        for (int i = 0; i < 4; ++i) {
            ckp[i] = (f32x4){0.f, 0.f, 0.f, 0.f};
            cvp[i] = (f32x4){0.f, 0.f, 0.f, 0.f};
        }
#pragma unroll
        for (int nt = 0; nt < 4; ++nt) {
            short8 bk0 = *reinterpret_cast<const short8*>(&swk[(nt * 16 + lane15) * 72 + q8]);
            short8 bk1 = *reinterpret_cast<const short8*>(&swk[(nt * 16 + lane15) * 72 + 32 + q8]);
            short8 bv0 = *reinterpret_cast<const short8*>(&swv[(nt * 16 + lane15) * 72 + q8]);
            short8 bv1 = *reinterpret_cast<const short8*>(&swv[(nt * 16 + lane15) * 72 + 32 + q8]);
            ckp[nt] = MFMA(ak0, bk0, ckp[nt]);
            cvp[nt] = MFMA(av0, bv0, cvp[nt]);
            ckp[nt] = MFMA(ak1, bk1, ckp[nt]);
            cvp[nt] = MFMA(av1, bv1, cvp[nt]);
        }
        const int srel = w * 16 + q4;
        const int sbase = it * 64;
#pragma unroll
        for (int nt = 0; nt < 4; ++nt) {
            const int x = nt * 16 + lane15;
            const float bk = sbk[x], bv = sbv[x];
            short ek[4], ev[4], es[4];
#pragma unroll
            for (int r = 0; r < 4; ++r) {
                float kk = elu1(ckp[nt][r] + bk);
                float vv = cvp[nt][r] + bv;
                ek[r] = f2bf(kk);
                ev[r] = f2bf(vv);
                es[r] = f2bf(vv * ssin[sbase + srel + r]);
            }
            st4(&kT [pb][x * 72 + srel], ek[0], ek[1], ek[2], ek[3]);
            st4(&vT [pb][x * 72 + srel], ev[0], ev[1], ev[2], ev[3]);
            st4(&vsT[pb][x * 72 + srel], es[0], es[1], es[2], es[3]);
        }
    };

    f32x4 ckv[4], ckvs[4];
#pragma unroll
    for (int i = 0; i < 4; ++i) {
        ckv[i]  = (f32x4){0.f, 0.f, 0.f, 0.f};
        ckvs[i] = (f32x4){0.f, 0.f, 0.f, 0.f};
    }
    float aks = 0.f, akss = 0.f;

    // preamble: j0 -> gA (consumed now), j1 -> gB; proj j0 -> buf0; j2 -> gA
    loadg(gA, 0);
    loadg(gB, 1);
    __syncthreads();                 // weights/ssin/bias visible
    projstore(gA, 0, 0);
    loadg(gA, 2);
    __syncthreads();                 // buf0 visible

    for (int it = 0; it < 8; ++it) {
        const int p = it & 1;
        if (it < 7) {
            float4* X = (it & 1) ? gA : gB;     // regs(j=it+1): j odd->gB, even->gA
            projstore(X, it + 1, p ^ 1);
            if (it < 5) loadg(X, it + 3);       // refill same set, 2-iter lookahead
        }
        // ---- kv / kvs GEMM from buf p: wave owns z-quarter w ----
#pragma unroll
        for (int kstep = 0; kstep < 2; ++kstep) {
            const int so = kstep * 32;
            short8 aV  = *reinterpret_cast<const short8*>(&vT [p][(w * 16 + lane15) * 72 + so + q8]);
            short8 aVS = *reinterpret_cast<const short8*>(&vsT[p][(w * 16 + lane15) * 72 + so + q8]);
#pragma unroll
            for (int nt = 0; nt < 4; ++nt) {
                short8 bK = *reinterpret_cast<const short8*>(&kT[p][(nt * 16 + lane15) * 72 + so + q8]);
                ckv[nt]  = MFMA(aV,  bK, ckv[nt]);
                ckvs[nt] = MFMA(aVS, bK, ckvs[nt]);
            }
        }
        // ---- ksum partials from buf p ----
        {
            const int sbase = it * 64;
            short8 k0 = *reinterpret_cast<const short8*>(&kT[p][l * 72 + w * 16]);
            short8 k1 = *reinterpret_cast<const short8*>(&kT[p][l * 72 + w * 16 + 8]);
#pragma unroll
            for (int e = 0; e < 8; ++e) {
                float fa = bf2f(k0[e]), fb = bf2f(k1[e]);
                aks  += fa + fb;
                akss += fa * ssin[sbase + w * 16 + e] + fb * ssin[sbase + w * 16 + 8 + e];
            }
        }
        __syncthreads();   // buf p^1 writes visible; all reads of p done
    }

    // ---- commit: coalesced non-atomic partial stores ([z][x], x = lane15) ----
    const int bh = b * HH + h;
    const size_t pbase = ((size_t)(chunk * 64) + bh) * 4096;
#pragma unroll
    for (int nt = 0; nt < 4; ++nt) {
        const int x = nt * 16 + lane15;
#pragma unroll
        for (int r = 0; r < 4; ++r) {
            const int z = w * 16 + q4 + r;
            pkv [pbase + z * 64 + x] = ckv[nt][r];
            pkvs[pbase + z * 64 + x] = ckvs[nt][r];
        }
    }
    sred[t] = aks; sred[256 + t] = akss;
    __syncthreads();
    if (t < 64) {
        pks[((size_t)(chunk * 64) + bh) * 128 + t] =
            sred[t] + sred[64 + t] + sred[128 + t] + sred[192 + t];
    } else if (t < 128) {
        int tt = t - 64;
        pks[((size_t)(chunk * 64) + bh) * 128 + t] =
            sred[256 + tt] + sred[320 + tt] + sred[384 + tt] + sred[448 + tt];
    }
}

// ---------------------------------------------------------------------------
// Reduce 8 chunk partials -> bf16 kv/kvs + fp32 ksums. (unchanged)
__global__ __launch_bounds__(256) void k_reduce(
    const float* __restrict__ pkv, const float* __restrict__ pkvs,
    const float* __restrict__ pks,
    short* __restrict__ kvb, short* __restrict__ kvsb,
    float* __restrict__ ksums)
{
    const int blk = blockIdx.x, t = threadIdx.x;
    if (blk < 512) {
        const float* src = (blk < 256) ? pkv : pkvs;
        short* dst = (blk < 256) ? kvb : kvsb;
        const int o4 = (blk & 255) * 256 + t;
        float4 s = make_float4(0.f, 0.f, 0.f, 0.f);
#pragma unroll
        for (int c = 0; c < 8; ++c) {
            float4 v = reinterpret_cast<const float4*>(src + (size_t)c * 262144)[o4];
            s.x += v.x; s.y += v.y; s.z += v.z; s.w += v.w;
        }
        st4(dst + (size_t)o4 * 4, f2bf(s.x), f2bf(s.y), f2bf(s.z), f2bf(s.w));
    } else {
        const int g = (blk - 512) * 256 + t;
        float4 s = make_float4(0.f, 0.f, 0.f, 0.f);
#pragma unroll
        for (int c = 0; c < 8; ++c) {
            float4 v = reinterpret_cast<const float4*>(pks + (size_t)c * 8192)[g];
            s.x += v.x; s.y += v.y; s.z += v.z; s.w += v.w;
        }
        reinterpret_cast<float4*>(ksums)[g] = s;
    }
}

// ---------------------------------------------------------------------------
// k_attn v8: grid (64 s-blocks of 64 rows, 4 b) = 256 blocks (1/CU).
// Block loops over ALL 16 heads; per-head operands (wq|kv|kvs|wd + ksums +
// bias) double-buffered in LDS: loads for h+1 issued at head top, committed
// at head end -> 1 barrier/head, staging latency hidden behind compute.
// Wave w owns rows [sblk*64 + w*16, +16): q-proj -> elu/den -> num -> dense,
// dense accumulated in registers across heads; q A-frags resident all 16.
__global__ __launch_bounds__(256, 1) void k_attn(
    const float* __restrict__ query, const float* __restrict__ wq_b,
    const short* __restrict__ wqTb,
    const short* __restrict__ kvb, const short* __restrict__ kvsb,
    const float* __restrict__ ksums,
    const short* __restrict__ wdTb, const float* __restrict__ dense_b,
    float* __restrict__ out)
{
    const int sblk = blockIdx.x, b = blockIdx.y;
    const int t = threadIdx.x, w = t >> 6, l = t & 63;
    const int l15 = l & 15, q8 = (l >> 4) * 8, q4 = (l >> 4) * 4;
    const int srow0 = sblk * 64 + w * 16;

    __shared__ short stg[2][4][64 * 72];   // [buf][wq|kv|kvs|wd][row*72+col]
    __shared__ float sks[2][128];
    __shared__ float sbq[2][64];
    __shared__ short wbuf[4][16 * 72];     // wave-private transform buffers

    short* myb = &wbuf[w][0];
    const int i0 = t * 2, i1 = t * 2 + 1;
    const int sr0 = i0 >> 3, sc0 = (i0 & 7) * 8;
    const int sr1 = i1 >> 3, sc1 = (i1 & 7) * 8;

    short8 rg[8];
    float rks = 0.f, rbq = 0.f;
    auto issue_loads = [&](int h) {
        const size_t bh = (size_t)(b * HH + h);
        const short8* gq = reinterpret_cast<const short8*>(wqTb + (size_t)h * 4096);
        const short8* gk = reinterpret_cast<const short8*>(kvb + bh * 4096);
        const short8* gs = reinterpret_cast<const short8*>(kvsb + bh * 4096);
        const short8* gd = reinterpret_cast<const short8*>(wdTb + (size_t)h * 4096);
        rg[0] = gq[i0]; rg[1] = gq[i1];
        rg[2] = gk[i0]; rg[3] = gk[i1];
        rg[4] = gs[i0]; rg[5] = gs[i1];
        rg[6] = gd[i0]; rg[7] = gd[i1];
        if (t < 128) rks = ksums[bh * 128 + t];
        else if (t < 192) rbq = wq_b[h * 64 + (t - 128)];
    };
    auto commit_stage = [&](int pb) {
        *reinterpret_cast<short8*>(&stg[pb][0][sr0 * 72 + sc0]) = rg[0];
        *reinterpret_cast<short8*>(&stg[pb][0][sr1 * 72 + sc1]) = rg[1];
        *reinterpret_cast<short8*>(&stg[pb][1][sr0 * 72 + sc0]) = rg[2];
        *reinterpret_cast<short8*>(&stg[pb][1][sr1 * 72 + sc1]) = rg[3];
        *reinterpret_cast<short8*>(&stg[pb][2][sr0 * 72 + sc0]) = rg[4];
        *reinterpret_cast<short8*>(&stg[pb][2][sr1 * 72 + sc1]) = rg[5];
        *reinterpret_cast<short8*>(&stg[pb][3][sr0 * 72 + sc0]) = rg[6];
        *reinterpret_cast<short8*>(&stg[pb][3][sr1 * 72 + sc1]) = rg[7];
        if (t < 128) sks[pb][t] = rks;
        else if (t < 192) sbq[pb][t - 128] = rbq;
    };

    // ---- resident per-wave state: q A-frags, cos+sin, dense bias ----
    short8 aq0, aq1;
    {
        const float* qp = query + ((size_t)b * SS + srow0 + l15) * 64 + q8;
        float4 f0 = *reinterpret_cast<const float4*>(qp);
        float4 f1 = *reinterpret_cast<const float4*>(qp + 4);
        float4 f2 = *reinterpret_cast<const float4*>(qp + 32);
        float4 f3 = *reinterpret_cast<const float4*>(qp + 36);
        aq0 = cvt8(f0, f1);
        aq1 = cvt8(f2, f3);
    }
    float ccr[4], db4[4];
#pragma unroll
    for (int r = 0; r < 4; ++r) {
        float ph = PI_C * (float)(srow0 + q4 + r) * (1.f / 4096.f);
        ccr[r] = __cosf(ph) + __sinf(ph);
    }
#pragma unroll
    for (int nt = 0; nt < 4; ++nt) db4[nt] = dense_b[nt * 16 + l15];

    f32x4 cd[4];
#pragma unroll
    for (int nt = 0; nt < 4; ++nt) cd[nt] = (f32x4){0.f, 0.f, 0.f, 0.f};

    // ---- stage head 0 ----
    issue_loads(0);
    commit_stage(0);
    __syncthreads();

    int pb = 0;
    for (int h = 0; h < HH; ++h) {
        if (h < HH - 1) issue_loads(h + 1);    // in flight during compute

        const short* swq  = &stg[pb][0][0];
        const short* skv  = &stg[pb][1][0];
        const short* skvs = &stg[pb][2][0];
        const short* swd  = &stg[pb][3][0];

        float bq4[4], ksx4[4], kss4[4];
#pragma unroll
        for (int nt = 0; nt < 4; ++nt) {
            bq4[nt]  = sbq[pb][nt * 16 + l15];
            ksx4[nt] = sks[pb][nt * 16 + l15];
            kss4[nt] = sks[pb][64 + nt * 16 + l15];
        }

        // ---- Q projection ----
        f32x4 cq[4];
#pragma unroll
        for (int nt = 0; nt < 4; ++nt) cq[nt] = (f32x4){0.f, 0.f, 0.f, 0.f};
#pragma unroll
        for (int nt = 0; nt < 4; ++nt) {
            short8 b0 = *reinterpret_cast<const short8*>(&swq[(nt * 16 + l15) * 72 + q8]);
            short8 b1 = *reinterpret_cast<const short8*>(&swq[(nt * 16 + l15) * 72 + 32 + q8]);
            cq[nt] = MFMA(aq0, b0, cq[nt]);
            cq[nt] = MFMA(aq1, b1, cq[nt]);
        }
        // ---- elu + den + q' -> wave-private LDS ([s][x]) ----
        float dp[4] = {0.f, 0.f, 0.f, 0.f};
#pragma unroll
        for (int nt = 0; nt < 4; ++nt) {
#pragma unroll
            for (int r = 0; r < 4; ++r) {
                float qv = elu1(cq[nt][r] + bq4[nt]);
                dp[r] = fmaf(qv, fmaf(ccr[r], kss4[nt], ksx4[nt]), dp[r]);
                myb[(q4 + r) * 72 + nt * 16 + l15] = f2bf(qv);
            }
        }
#pragma unroll
        for (int m = 1; m <= 8; m <<= 1) {
#pragma unroll
            for (int r = 0; r < 4; ++r) dp[r] += __shfl_xor(dp[r], m);
        }
        float invd[4];
#pragma unroll
        for (int r = 0; r < 4; ++r) invd[r] = 1.f / (dp[r] + 1e-5f);

        // ---- q' A-frags (wave-ordered DS, no barrier) ----
        short8 a0 = *reinterpret_cast<const short8*>(&myb[l15 * 72 + q8]);
        short8 a1 = *reinterpret_cast<const short8*>(&myb[l15 * 72 + 32 + q8]);

        // ---- numerator GEMMs ----
        f32x4 ckv[4], ckvs[4];
#pragma unroll
        for (int nt = 0; nt < 4; ++nt) {
            ckv[nt]  = (f32x4){0.f, 0.f, 0.f, 0.f};
            ckvs[nt] = (f32x4){0.f, 0.f, 0.f, 0.f};
        }
#pragma unroll
        for (int nt = 0; nt < 4; ++nt) {
            short8 b0 = *reinterpret_cast<const short8*>(&skv [(nt * 16 + l15) * 72 + q8]);
            short8 b1 = *reinterpret_cast<const short8*>(&skv [(nt * 16 + l15) * 72 + 32 + q8]);
            short8 c0 = *reinterpret_cast<const short8*>(&skvs[(nt * 16 + l15) * 72 + q8]);
            short8 c1 = *reinterpret_cast<const short8*>(&skvs[(nt * 16 + l15) * 72 + 32 + q8]);
            ckv[nt]  = MFMA(a0, b0, ckv[nt]);
            ckv[nt]  = MFMA(a1, b1, ckv[nt]);
            ckvs[nt] = MFMA(a0, c0, ckvs[nt]);
            ckvs[nt] = MFMA(a1, c1, ckvs[nt]);
        }
        // ---- combine + O -> wave-private LDS ([s][z]) ----
#pragma unroll
        for (int nt = 0; nt < 4; ++nt) {
#pragma unroll
            for (int r = 0; r < 4; ++r) {
                float o = fmaf(ccr[r], ckvs[nt][r], ckv[nt][r]) * invd[r];
                myb[(q4 + r) * 72 + nt * 16 + l15] = f2bf(o);
            }
        }
        short8 a30 = *reinterpret_cast<const short8*>(&myb[l15 * 72 + q8]);
        short8 a31 = *reinterpret_cast<const short8*>(&myb[l15 * 72 + 32 + q8]);

        // ---- dense GEMM, accumulated across heads ----
#pragma unroll
        for (int nt = 0; nt < 4; ++nt) {
            short8 b0 = *reinterpret_cast<const short8*>(&swd[(nt * 16 + l15) * 72 + q8]);
            short8 b1 = *reinterpret_cast<const short8*>(&swd[(nt * 16 + l15) * 72 + 32 + q8]);
            cd[nt] = MFMA(a30, b0, cd[nt]);
            cd[nt] = MFMA(a31, b1, cd[nt]);
        }

        // ---- commit next head's staging (global loads had full compute to land) ----
        if (h < HH - 1) commit_stage(pb ^ 1);
        __syncthreads();
        pb ^= 1;
    }

    // ---- epilogue: bias + fp32 store ----
#pragma unroll
    for (int nt = 0; nt < 4; ++nt) {
        const int c = nt * 16 + l15;
#pragma unroll
        for (int r = 0; r < 4; ++r)
            out[((size_t)b * SS + srow0 + q4 + r) * 64 + c] = cd[nt][r] + db4[nt];
    }
}

// ---------------------------------------------------------------------------
extern "C" void kernel_launch(void* const* d_in, const int* in_sizes, int n_in,
                              void* d_out, int out_size, void* d_ws, size_t ws_size,
                              hipStream_t stream) {
    const float* query   = (const float*)d_in[0];
    const float* key     = (const float*)d_in[1];
    const float* value   = (const float*)d_in[2];
    // d_in[3] attn_mask unused
    const float* wq_w    = (const float*)d_in[4];
    const float* wq_b    = (const float*)d_in[5];
    const float* wk_w    = (const float*)d_in[6];
    const float* wk_b    = (const float*)d_in[7];
    const float* wv_w    = (const float*)d_in[8];
    const float* wv_b    = (const float*)d_in[9];
    const float* dense_w = (const float*)d_in[10];
    const float* dense_b = (const float*)d_in[11];
    float* out = (float*)d_out;

    char* ws = (char*)d_ws;
    short* wT    = (short*)(ws);             // wq|wk|wv|wd, 65536 shorts each
    short* kvb   = (short*)(ws + 524288);
    short* kvsb  = (short*)(ws + 1048576);
    float* ksums = (float*)(ws + 1572864);
    float* pkv   = (float*)(ws + 1605632);
    float* pkvs  = (float*)(ws + 9994240);
    float* pks   = (float*)(ws + 18382848);
    short* wqTb  = wT;
    short* wkTb  = wT + 65536;
    short* wvTb  = wT + 131072;
    short* wdTb  = wT + 196608;

    hipLaunchKernelGGL(k_prep, dim3(16, 4), dim3(256), 0, stream,
                       wq_w, wk_w, wv_w, dense_w, wT);
    hipLaunchKernelGGL(k_phase1, dim3(8, HH, BB), dim3(256), 0, stream,
                       key, value, wk_b, wv_b, wkTb, wvTb, pkv, pkvs, pks);
    hipLaunchKernelGGL(k_reduce, dim3(520), dim3(256), 0, stream,
                       pkv, pkvs, pks, kvb, kvsb, ksums);
    hipLaunchKernelGGL(k_attn, dim3(SS / 64, BB), dim3(256), 0, stream,
                       query, wq_b, wqTb, kvb, kvsb, ksums, wdTb, dense_b, out);
}